// Round 6
// baseline (74.273 us; speedup 1.0000x reference)
//
#include <hip/hip_runtime.h>

#define N_NODES 100000
#define DEG 32
#define DIM 256
#define NRT 782          // row-tiles of 128
#define NBB 256          // row-tile slots per col-half

typedef _Float16 f16x8 __attribute__((ext_vector_type(8)));
typedef float f32x4 __attribute__((ext_vector_type(4)));

// Wswz layout: f16x8 units, idx = (kt*16 + nt)*64 + lane, kt in [0,8), nt in [0,16).
// Unit element j holds W[kt*32 + 4*(lane>>4) + (j&3) + 16*(j>>2)][nt*16 + (lane&15)]
// (B fragment for mfma_f32_16x16x32_f16; A uses the identical (lane,j)->k map, so
//  any k-permutation error cancels in the contraction.)
__global__ void wprep_kernel(const float* __restrict__ W, _Float16* __restrict__ Wswz) {
    int tid = blockIdx.x * blockDim.x + threadIdx.x;  // 0..8191
    int l = tid & 63;
    int frag = tid >> 6;
    int kt = frag >> 4;
    int nt = frag & 15;
    int col = nt * 16 + (l & 15);
    int kbase = kt * 32 + ((l >> 4) << 2);
    f16x8 v;
#pragma unroll
    for (int j = 0; j < 8; ++j) {
        int k = kbase + (j & 3) + ((j >> 2) << 4);
        v[j] = (_Float16)W[(size_t)k * DIM + col];
    }
    *reinterpret_cast<f16x8*>(Wswz + (size_t)tid * 8) = v;
}

__device__ __forceinline__ f16x8 cvt_a(float4 lo, float4 hi) {
    f16x8 af;
    af[0] = (_Float16)lo.x; af[1] = (_Float16)lo.y;
    af[2] = (_Float16)lo.z; af[3] = (_Float16)lo.w;
    af[4] = (_Float16)hi.x; af[5] = (_Float16)hi.y;
    af[6] = (_Float16)hi.z; af[7] = (_Float16)hi.w;
    return af;
}

// Persistent-B blocks: 512 blocks x 512 threads. Block b: col-half nh = b>>8,
// row-tiles (bb + 256k)*128 for k=0..ntiles-1. B staged in LDS ONCE; across
// tiles the next tile's A loads are issued inside the current tile's MFMA
// loop (vmcnt stream) while MFMA consumes LDS (lgkmcnt stream) -> continuous
// HBM read duty cycle. Adjacency prefetched one tile ahead.
__launch_bounds__(512, 4)
__global__ void agg_kernel(const float* __restrict__ F, const float* __restrict__ Adj,
                           const _Float16* __restrict__ Wswz, float* __restrict__ out) {
    __shared__ _Float16 sB[64 * 64 * 8];    // 64 KB: chunk c=kt*8+np at ((c*64)+l)*8
    __shared__ float s_amax[2][128];
    __shared__ float s_amin[2][128];

    const int b  = blockIdx.x;
    const int nh = b >> 8;
    const int bb = b & (NBB - 1);
    const int n0 = nh * 128;
    const int t  = threadIdx.x;
    const int wv = t >> 6;
    const int l  = t & 63;
    const int lg = l >> 4;
    const int ll = l & 15;

    // ---- stage B col-half into LDS (once per block) ----
#pragma unroll
    for (int i = 0; i < 8; ++i) {
        int c = wv * 8 + i;
        int kt = c >> 3, np = c & 7;
        int srcfrag = kt * 16 + nh * 8 + np;
        f16x8 v = *reinterpret_cast<const f16x8*>(Wswz + ((size_t)srcfrag * 64 + l) * 8);
        *reinterpret_cast<f16x8*>(&sB[((size_t)c * 64 + l) * 8]) = v;
    }

    const int ntiles = (bb < NRT - 3 * NBB) ? 4 : 3;   // 782 = 3*256 + 14

    // ---- prime adjacency for tile 0 (4 threads/row, 8 floats each) ----
    const int rrow = t >> 2;          // 0..127
    const int q    = t & 3;
    float4 adjp0, adjp1;
    {
        int r0 = bb * 128 + rrow;     // tile-0 rows always < N
        const float4* ap = reinterpret_cast<const float4*>(Adj + (size_t)r0 * DEG) + q * 2;
        adjp0 = ap[0]; adjp1 = ap[1];
    }

    // ---- prime A for tile 0 ----
    f16x8 a16[8];
    {
        int rowA = bb * 128 + wv * 16 + ll;
        const float4* Af4 = reinterpret_cast<const float4*>(F + (size_t)rowA * DIM) + lg;
        float4 plo[8], phi[8];
#pragma unroll
        for (int kt = 0; kt < 8; ++kt) { plo[kt] = Af4[kt * 8]; phi[kt] = Af4[kt * 8 + 4]; }
#pragma unroll
        for (int kt = 0; kt < 8; ++kt) a16[kt] = cvt_a(plo[kt], phi[kt]);
    }

    __syncthreads();   // B staged

    f32x4 acc[8];
#pragma unroll
    for (int np = 0; np < 8; ++np) acc[np] = (f32x4){0.f, 0.f, 0.f, 0.f};

    const f16x8* Bl = reinterpret_cast<const f16x8*>(sB) + l;

    for (int k = 0; k < ntiles; ++k) {
        const int m0  = (bb + NBB * k) * 128;
        const int par = k & 1;
        const int m0n = (bb + NBB * (k + 1)) * 128;   // next tile (clamped per row)

        // publish current tile's adjacency minmax; prefetch next tile's
        {
            float mx = fmaxf(fmaxf(adjp0.x, adjp0.y), fmaxf(adjp0.z, adjp0.w));
            mx = fmaxf(mx, fmaxf(fmaxf(adjp1.x, adjp1.y), fmaxf(adjp1.z, adjp1.w)));
            float mn = fminf(fminf(adjp0.x, adjp0.y), fminf(adjp0.z, adjp0.w));
            mn = fminf(mn, fminf(fminf(adjp1.x, adjp1.y), fminf(adjp1.z, adjp1.w)));
            mx = fmaxf(mx, __shfl_xor(mx, 1)); mn = fminf(mn, __shfl_xor(mn, 1));
            mx = fmaxf(mx, __shfl_xor(mx, 2)); mn = fminf(mn, __shfl_xor(mn, 2));
            if (q == 0) { s_amax[par][rrow] = mx; s_amin[par][rrow] = mn; }
            int rn = m0n + rrow;
            rn = rn < N_NODES ? rn : (N_NODES - 1);
            const float4* ap = reinterpret_cast<const float4*>(Adj + (size_t)rn * DEG) + q * 2;
            adjp0 = ap[0]; adjp1 = ap[1];
        }

        // next-tile A base (row-clamped; last tile reads cached row N-1)
        int rowAn = m0n + wv * 16 + ll;
        rowAn = rowAn < N_NODES ? rowAn : (N_NODES - 1);
        const float4* Afn = reinterpret_cast<const float4*>(F + (size_t)rowAn * DIM) + lg;

        float4 rlo[8], rhi[8];
        // ---- MFMA over current tile; issue next tile's A chunk per step ----
#pragma unroll
        for (int kt = 0; kt < 8; ++kt) {
            rlo[kt] = Afn[kt * 8];
            rhi[kt] = Afn[kt * 8 + 4];
#pragma unroll
            for (int np = 0; np < 8; ++np) {
                f16x8 bfr = Bl[(kt * 8 + np) * 64];
                acc[np] = __builtin_amdgcn_mfma_f32_16x16x32_f16(a16[kt], bfr, acc[np], 0, 0, 0);
            }
            if (kt >= 4) a16[kt - 4] = cvt_a(rlo[kt - 4], rhi[kt - 4]);
        }

        __syncthreads();   // s_amax[par] visible; all reads of sB for this tile done

        // ---- epilogue: out = max(amax*p, amin*p, 0) for current tile ----
        const int rbase = wv * 16 + 4 * lg;
#pragma unroll
        for (int r = 0; r < 4; ++r) {
            const int lr = rbase + r;
            const int row = m0 + lr;
            if (row < N_NODES) {
                const float amax = s_amax[par][lr];
                const float amin = s_amin[par][lr];
                float* orow = out + (size_t)row * DIM + n0 + ll;
#pragma unroll
                for (int np = 0; np < 8; ++np) {
                    float p = acc[np][r];
                    orow[np * 16] = fmaxf(fmaxf(amax * p, amin * p), 0.0f);
                }
            }
        }

        // finish converting next tile's A (chunks 4..7) and reset acc
#pragma unroll
        for (int c = 4; c < 8; ++c) a16[c] = cvt_a(rlo[c], rhi[c]);
#pragma unroll
        for (int np = 0; np < 8; ++np) acc[np] = (f32x4){0.f, 0.f, 0.f, 0.f};
    }
}

extern "C" void kernel_launch(void* const* d_in, const int* in_sizes, int n_in,
                              void* d_out, int out_size, void* d_ws, size_t ws_size,
                              hipStream_t stream) {
    const float* F   = (const float*)d_in[0];
    const float* Adj = (const float*)d_in[1];
    const float* W   = (const float*)d_in[2];
    float* out = (float*)d_out;
    _Float16* Wswz = (_Float16*)d_ws;   // 256*256*2 = 128 KB

    hipLaunchKernelGGL(wprep_kernel, dim3(32), dim3(256), 0, stream, W, Wswz);
    hipLaunchKernelGGL(agg_kernel, dim3(512), dim3(512), 0, stream, F, Adj, Wswz, out);
}

// Round 7
// 50.191 us; speedup vs baseline: 1.4798x; 1.4798x over previous
//
#include <hip/hip_runtime.h>

#define N_NODES 100000
#define DEG 32
#define DIM 256

typedef _Float16 f16x8 __attribute__((ext_vector_type(8)));
typedef float f32x4 __attribute__((ext_vector_type(4)));

// Wswz layout: f16x8 units, idx = (kt*16 + nt)*64 + lane, kt in [0,8), nt in [0,16).
// Unit element j holds W[kt*32 + 4*(lane>>4) + (j&3) + 16*(j>>2)][nt*16 + (lane&15)]
// (B fragment for mfma_f32_16x16x32_f16; A uses the identical (lane,j)->k map, so
//  any k-permutation error cancels in the contraction.)
__global__ void wprep_kernel(const float* __restrict__ W, _Float16* __restrict__ Wswz) {
    int tid = blockIdx.x * blockDim.x + threadIdx.x;  // 0..8191
    int l = tid & 63;
    int frag = tid >> 6;
    int kt = frag >> 4;
    int nt = frag & 15;
    int col = nt * 16 + (l & 15);
    int kbase = kt * 32 + ((l >> 4) << 2);
    f16x8 v;
#pragma unroll
    for (int j = 0; j < 8; ++j) {
        int k = kbase + (j & 3) + ((j >> 2) << 4);
        v[j] = (_Float16)W[(size_t)k * DIM + col];
    }
    *reinterpret_cast<f16x8*>(Wswz + (size_t)tid * 8) = v;
}

__device__ __forceinline__ f16x8 cvt_a(float4 lo, float4 hi) {
    f16x8 af;
    af[0] = (_Float16)lo.x; af[1] = (_Float16)lo.y;
    af[2] = (_Float16)lo.z; af[3] = (_Float16)lo.w;
    af[4] = (_Float16)hi.x; af[5] = (_Float16)hi.y;
    af[6] = (_Float16)hi.z; af[7] = (_Float16)hi.w;
    return af;
}

// Block = 256 threads (4 waves). Tile = 64 rows x 256 cols, processed as four
// 64-col phases. A (64 rows) loaded ONCE into f16 registers and reused across
// all phases; B quarter (32 KB) staged per phase -> 4 resident blocks/CU,
// phase-staggered, keeping the HBM read pipe busy. Stage loads are issued
// BEFORE the A burst so their ds_writes don't queue behind HBM-latency loads.
__launch_bounds__(256, 4)
__global__ void agg_kernel(const float* __restrict__ F, const float* __restrict__ Adj,
                           const _Float16* __restrict__ Wswz, float* __restrict__ out) {
    __shared__ _Float16 sB[32 * 64 * 8];   // 32 KB: chunk c=kt*4+np at ((c*64)+l)*8
    __shared__ float s_amax[64];
    __shared__ float s_amin[64];

    const int bx = blockIdx.x;
    const int m0 = bx * 64;
    const int t  = threadIdx.x;
    const int wv = t >> 6;
    const int l  = t & 63;
    const int lg = l >> 4;
    const int ll = l & 15;

    // ---- stage B quarter 0 (L2-resident source; 8 chunks of 1 KB per wave) ----
#pragma unroll
    for (int i = 0; i < 8; ++i) {
        int c = wv * 8 + i;                 // c = kt*4 + np
        int kt = c >> 2, np = c & 3;
        int srcfrag = kt * 16 + np;         // quarter 0: nt = np
        f16x8 v = *reinterpret_cast<const f16x8*>(Wswz + ((size_t)srcfrag * 64 + l) * 8);
        *reinterpret_cast<f16x8*>(&sB[((size_t)c * 64 + l) * 8]) = v;
    }

    // ---- adjacency loads (4 threads per row, 32 B each) ----
    const int rrow = t >> 2;                // 0..63
    const int q    = t & 3;
    int radj = m0 + rrow;
    radj = radj < N_NODES ? radj : (N_NODES - 1);
    const float4* ap = reinterpret_cast<const float4*>(Adj + (size_t)radj * DEG) + q * 2;
    float4 ad0 = ap[0], ad1 = ap[1];

    // ---- A burst: 16 dwordx4 per lane, issued after stage+adj loads ----
    int rowA = m0 + wv * 16 + ll;
    rowA = rowA < N_NODES ? rowA : (N_NODES - 1);
    const float4* Af4 = reinterpret_cast<const float4*>(F + (size_t)rowA * DIM) + lg;
    float4 plo[8], phi[8];
#pragma unroll
    for (int kt = 0; kt < 8; ++kt) { plo[kt] = Af4[kt * 8]; phi[kt] = Af4[kt * 8 + 4]; }

    // ---- adjacency reduce (waits only on adj loads; A still in flight) ----
    float mx = fmaxf(fmaxf(ad0.x, ad0.y), fmaxf(ad0.z, ad0.w));
    mx = fmaxf(mx, fmaxf(fmaxf(ad1.x, ad1.y), fmaxf(ad1.z, ad1.w)));
    float mn = fminf(fminf(ad0.x, ad0.y), fminf(ad0.z, ad0.w));
    mn = fminf(mn, fminf(fminf(ad1.x, ad1.y), fminf(ad1.z, ad1.w)));
    mx = fmaxf(mx, __shfl_xor(mx, 1)); mn = fminf(mn, __shfl_xor(mn, 1));
    mx = fmaxf(mx, __shfl_xor(mx, 2)); mn = fminf(mn, __shfl_xor(mn, 2));
    if (q == 0) { s_amax[rrow] = mx; s_amin[rrow] = mn; }

    // ---- convert A to f16 fragments ----
    f16x8 a16[8];
#pragma unroll
    for (int kt = 0; kt < 8; ++kt) a16[kt] = cvt_a(plo[kt], phi[kt]);

    __syncthreads();   // sB quarter 0 + s_amax visible

    const f16x8* Bl = reinterpret_cast<const f16x8*>(sB) + l;
    const int rbase = wv * 16 + 4 * lg;

#pragma unroll
    for (int p = 0; p < 4; ++p) {
        f32x4 acc[4];
#pragma unroll
        for (int np = 0; np < 4; ++np) acc[np] = (f32x4){0.f, 0.f, 0.f, 0.f};

        // ---- pure ds_read -> MFMA stream over this col quarter ----
#pragma unroll
        for (int kt = 0; kt < 8; ++kt) {
#pragma unroll
            for (int np = 0; np < 4; ++np) {
                f16x8 b = Bl[(kt * 4 + np) * 64];
                acc[np] = __builtin_amdgcn_mfma_f32_16x16x32_f16(a16[kt], b, acc[np], 0, 0, 0);
            }
        }
        __syncthreads();   // all waves done reading sB for phase p

        // ---- issue next quarter's stage (L2) ----
        if (p < 3) {
#pragma unroll
            for (int i = 0; i < 8; ++i) {
                int c = wv * 8 + i;
                int kt = c >> 2, np = c & 3;
                int srcfrag = kt * 16 + (p + 1) * 4 + np;
                f16x8 v = *reinterpret_cast<const f16x8*>(Wswz + ((size_t)srcfrag * 64 + l) * 8);
                *reinterpret_cast<f16x8*>(&sB[((size_t)c * 64 + l) * 8]) = v;
            }
        }

        // ---- epilogue stores (overlap the stage latency) ----
#pragma unroll
        for (int r = 0; r < 4; ++r) {
            const int lr = rbase + r;
            const int row = m0 + lr;
            if (row < N_NODES) {
                const float amax = s_amax[lr];
                const float amin = s_amin[lr];
                float* orow = out + (size_t)row * DIM + p * 64 + ll;
#pragma unroll
                for (int np = 0; np < 4; ++np) {
                    float v = acc[np][r];
                    orow[np * 16] = fmaxf(fmaxf(amax * v, amin * v), 0.0f);
                }
            }
        }

        if (p < 3) __syncthreads();   // staged quarter visible
    }
}

extern "C" void kernel_launch(void* const* d_in, const int* in_sizes, int n_in,
                              void* d_out, int out_size, void* d_ws, size_t ws_size,
                              hipStream_t stream) {
    const float* F   = (const float*)d_in[0];
    const float* Adj = (const float*)d_in[1];
    const float* W   = (const float*)d_in[2];
    float* out = (float*)d_out;
    _Float16* Wswz = (_Float16*)d_ws;   // 256*256*2 = 128 KB

    hipLaunchKernelGGL(wprep_kernel, dim3(32), dim3(256), 0, stream, W, Wswz);
    const int nblk = (N_NODES + 63) / 64;   // 1563
    hipLaunchKernelGGL(agg_kernel, dim3(nblk), dim3(256), 0, stream, F, Adj, Wswz, out);
}